// Round 8
// baseline (664.327 us; speedup 1.0000x reference)
//
#include <hip/hip_runtime.h>
#include <hip/hip_fp16.h>

#define NN 100000
#define NE 1600000
#define NG 2000
#define DIM 256
#define NF 4
#define SCAN_B 1024
#define NBLK ((NN + SCAN_B - 1) / SCAN_B)   // 98
#define SCAT_BLK 2048
#define WCONV_BLK 256
#define EMB_BLK ((NN * 64) / 256)           // 25000

using half8 = __attribute__((ext_vector_type(8))) _Float16;
using f32x4 = __attribute__((ext_vector_type(4))) float;

__device__ inline float4 h4_to_f4(uint2 v) {
    __half2 a = *reinterpret_cast<__half2*>(&v.x);
    __half2 b = *reinterpret_cast<__half2*>(&v.y);
    float2 fa = __half22float2(a);
    float2 fb = __half22float2(b);
    return make_float4(fa.x, fa.y, fb.x, fb.y);
}

__device__ inline uint2 f4_to_h4(float4 r) {
    __half2 a = __floats2half2_rn(r.x, r.y);
    __half2 b = __floats2half2_rn(r.z, r.w);
    uint2 o;
    o.x = *reinterpret_cast<uint*>(&a);
    o.y = *reinterpret_cast<uint*>(&b);
    return o;
}

__device__ inline void add8(float4& a0, float4& a1, uint4 u) {
    uint2 lo2; lo2.x = u.x; lo2.y = u.y;
    uint2 hi2; hi2.x = u.z; hi2.y = u.w;
    float4 lo = h4_to_f4(lo2);
    float4 hi = h4_to_f4(hi2);
    a0.x += lo.x; a0.y += lo.y; a0.z += lo.z; a0.w += lo.w;
    a1.x += hi.x; a1.y += hi.y; a1.z += hi.z; a1.w += hi.w;
}

// ---------------- degree counting + slot capture ----------------
__global__ void k_count(const int* __restrict__ src, const int* __restrict__ dst,
                        int* __restrict__ outd, int* __restrict__ ind,
                        ushort* __restrict__ slots) {
    int i = blockIdx.x * blockDim.x + threadIdx.x;
    int stride = gridDim.x * blockDim.x;
    for (; i < NE; i += stride) {
        atomicAdd(&outd[src[i]], 1);
        int s = atomicAdd(&ind[dst[i]], 1);
        slots[i] = (ushort)s;
    }
}

// ---------------- multi-block exclusive scan of in-degrees ----------------
__global__ __launch_bounds__(1024) void k_scan1(const int* __restrict__ deg,
                                                int* __restrict__ locex,
                                                int* __restrict__ partials) {
    __shared__ int sm[SCAN_B];
    int t = threadIdx.x;
    int i = blockIdx.x * SCAN_B + t;
    int v = (i < NN) ? deg[i] : 0;
    sm[t] = v;
    __syncthreads();
    for (int off = 1; off < SCAN_B; off <<= 1) {
        int u = (t >= off) ? sm[t - off] : 0;
        __syncthreads();
        sm[t] += u;
        __syncthreads();
    }
    if (i < NN) locex[i] = sm[t] - v;
    if (t == SCAN_B - 1) partials[blockIdx.x] = sm[t];
}

__global__ __launch_bounds__(128) void k_scan2(int* __restrict__ partials,
                                               int* __restrict__ rowptr_last) {
    __shared__ int sm[128];
    int t = threadIdx.x;
    int v = (t < NBLK) ? partials[t] : 0;
    sm[t] = v;
    __syncthreads();
    for (int off = 1; off < 128; off <<= 1) {
        int u = (t >= off) ? sm[t - off] : 0;
        __syncthreads();
        sm[t] += u;
        __syncthreads();
    }
    if (t < NBLK) partials[t] = sm[t] - v;
    if (t == 127) *rowptr_last = sm[127];
}

// phase 3: rowptr = locex + block offset; norms fused (per-node pass)
__global__ __launch_bounds__(1024) void k_scan3(const int* __restrict__ locex,
                                                const int* __restrict__ partials,
                                                const int* __restrict__ outd,
                                                const int* __restrict__ ind,
                                                int* __restrict__ rowptr,
                                                float* __restrict__ onorm,
                                                float* __restrict__ inorm) {
    int i = blockIdx.x * SCAN_B + threadIdx.x;
    if (i < NN) {
        rowptr[i] = locex[i] + partials[blockIdx.x];
        int od = outd[i];
        int id = ind[i];
        onorm[i] = od > 0 ? rsqrtf((float)od) : 0.f;
        inorm[i] = id > 0 ? rsqrtf((float)id) : 0.f;
    }
}

// -------- FUSED: atomic-free scatter | W->Wt fp16 | embedding sum + onorm prescale --------
// All three depend only on scan3 outputs (rowptr/onorm) + raw inputs; the embed range's
// streaming reads overlap the scatter range's random-write drain on otherwise-idle CUs.
__global__ void k_scatter_wconv_embed(const int* __restrict__ src, const int* __restrict__ dst,
                                      const int* __restrict__ rowptr,
                                      const ushort* __restrict__ slots,
                                      int* __restrict__ col,
                                      const float* __restrict__ W1, const float* __restrict__ W2,
                                      ushort* __restrict__ Wt1, ushort* __restrict__ Wt2,
                                      const int* __restrict__ feat, const float* __restrict__ emb,
                                      const float* __restrict__ onorm, ushort* __restrict__ h) {
    int tid = threadIdx.x;
    if (blockIdx.x < SCAT_BLK) {
        int i = blockIdx.x * 256 + tid;
        const int stride = SCAT_BLK * 256;
        for (; i < NE; i += stride) {
            int d = dst[i];
            col[rowptr[d] + (int)slots[i]] = src[i];
        }
    } else if (blockIdx.x < SCAT_BLK + WCONV_BLK) {
        int idx = (blockIdx.x - SCAT_BLK) * 256 + tid;  // 65536
        if (idx >= DIM * DIM) return;
        int k = idx >> 8;
        int n = idx & 255;
        __fp16 a = (__fp16)W1[idx];
        __fp16 b = (__fp16)W2[idx];
        reinterpret_cast<__fp16*>(Wt1)[n * DIM + k] = a;
        reinterpret_cast<__fp16*>(Wt2)[n * DIM + k] = b;
    } else {
        int idx = (blockIdx.x - SCAT_BLK - WCONV_BLK) * 256 + tid;  // NN*64 total
        int node = idx >> 6;
        int g = idx & 63;
        if (node >= NN) return;
        const int4 f = *reinterpret_cast<const int4*>(feat + node * 4);
        const float4* emb4 = reinterpret_cast<const float4*>(emb);
        float4 a = emb4[(long)f.x * 64 + g];
        float4 b = emb4[(long)f.y * 64 + g];
        float4 c = emb4[(long)f.z * 64 + g];
        float4 d = emb4[(long)f.w * 64 + g];
        float sc = onorm[node];
        float4 r;
        r.x = (a.x + b.x + c.x + d.x) * sc;
        r.y = (a.y + b.y + c.y + d.y) * sc;
        r.z = (a.z + b.z + c.z + d.z) * sc;
        r.w = (a.w + b.w + c.w + d.w) * sc;
        reinterpret_cast<uint2*>(h)[(long)node * 64 + g] = f4_to_h4(r);
    }
}

// ---------------- aggregation: one wave per dst node ----------------
// 16B/lane loads: lanes 0-31 fetch even edges' rows, lanes 32-63 odd edges'.
// MODE 0: hout = relu(acc * inorm) * onorm ; MODE 1: hout = acc * inorm
template <int MODE>
__global__ void k_agg(const int* __restrict__ rowptr, const int* __restrict__ col,
                      const ushort* __restrict__ hin, const float* __restrict__ inorm,
                      const float* __restrict__ onorm, ushort* __restrict__ hout) {
    int wid = (blockIdx.x * blockDim.x + threadIdx.x) >> 6;
    int lane = threadIdx.x & 63;
    if (wid >= NN) return;
    int half = lane >> 5;
    int l32 = lane & 31;
    int e0 = rowptr[wid];
    int e1 = rowptr[wid + 1];
    const uint4* hin4 = reinterpret_cast<const uint4*>(hin);
    float4 aA0 = {0,0,0,0}, aA1 = {0,0,0,0};
    float4 aB0 = {0,0,0,0}, aB1 = {0,0,0,0};
    int e = e0;
    for (; e + 8 <= e1; e += 8) {
        int s0 = col[e + 0 + half];
        int s1 = col[e + 2 + half];
        int s2 = col[e + 4 + half];
        int s3 = col[e + 6 + half];
        uint4 u0 = hin4[(long)s0 * 32 + l32];
        uint4 u1 = hin4[(long)s1 * 32 + l32];
        uint4 u2 = hin4[(long)s2 * 32 + l32];
        uint4 u3 = hin4[(long)s3 * 32 + l32];
        add8(aA0, aA1, u0);
        add8(aB0, aB1, u1);
        add8(aA0, aA1, u2);
        add8(aB0, aB1, u3);
    }
    for (; e < e1; e += 2) {
        int idx = e + half;
        if (idx < e1) {
            int s = col[idx];
            uint4 u = hin4[(long)s * 32 + l32];
            add8(aA0, aA1, u);
        }
    }
    float f[8];
    f[0] = aA0.x + aB0.x; f[1] = aA0.y + aB0.y; f[2] = aA0.z + aB0.z; f[3] = aA0.w + aB0.w;
    f[4] = aA1.x + aB1.x; f[5] = aA1.y + aB1.y; f[6] = aA1.z + aB1.z; f[7] = aA1.w + aB1.w;
#pragma unroll
    for (int j = 0; j < 8; ++j) f[j] += __shfl_xor(f[j], 32);

    float sc = inorm[wid];
    float4 r0, r1;
    if (MODE == 0) {
        float on = onorm[wid];
        r0.x = fmaxf(f[0] * sc, 0.f) * on;
        r0.y = fmaxf(f[1] * sc, 0.f) * on;
        r0.z = fmaxf(f[2] * sc, 0.f) * on;
        r0.w = fmaxf(f[3] * sc, 0.f) * on;
        r1.x = fmaxf(f[4] * sc, 0.f) * on;
        r1.y = fmaxf(f[5] * sc, 0.f) * on;
        r1.z = fmaxf(f[6] * sc, 0.f) * on;
        r1.w = fmaxf(f[7] * sc, 0.f) * on;
    } else {
        r0.x = f[0] * sc; r0.y = f[1] * sc; r0.z = f[2] * sc; r0.w = f[3] * sc;
        r1.x = f[4] * sc; r1.y = f[5] * sc; r1.z = f[6] * sc; r1.w = f[7] * sc;
    }
    if (half == 0) {
        uint2 lo = f4_to_h4(r0);
        uint2 hi = f4_to_h4(r1);
        uint4 o; o.x = lo.x; o.y = lo.y; o.z = hi.x; o.w = hi.y;
        reinterpret_cast<uint4*>(hout)[(long)wid * 32 + l32] = o;
    }
}

// ---------------- MFMA GEMM: y[NN,256] = x[NN,256] @ W[256,256] ----------------
// 512 threads (8 waves); wave computes 48 rows (3 m-frags) x 256 cols; block = 384 rows.
__global__ __launch_bounds__(512, 2) void k_gemm(const ushort* __restrict__ x,
                                                 const ushort* __restrict__ Wt,
                                                 ushort* __restrict__ y) {
    __shared__ char wl[131072];
    int tid = threadIdx.x;
    const uint4* Wt4 = reinterpret_cast<const uint4*>(Wt);
#pragma unroll
    for (int it = 0; it < 16; ++it) {
        int chunk = it * 512 + tid;      // 0..8191 16B-chunks
        int n = chunk >> 5;              // row 0..255
        int c16 = chunk & 31;
        uint4 v = Wt4[chunk];
        int off = ((n << 9) + (c16 << 4)) ^ ((n & 7) << 4);
        *reinterpret_cast<uint4*>(&wl[off]) = v;
    }
    __syncthreads();

    int w = tid >> 6;
    int l = tid & 63;
    int wrow = blockIdx.x * 384 + w * 48;
    int lrow = l & 15;
    int lk = l >> 4;

    f32x4 acc[3][16];
#pragma unroll
    for (int m = 0; m < 3; ++m)
#pragma unroll
        for (int n = 0; n < 16; ++n) acc[m][n] = {0.f, 0.f, 0.f, 0.f};

    const char* xb = reinterpret_cast<const char*>(x);
    int r0 = wrow + lrow;
    int r1 = r0 + 16;
    int r2 = r0 + 32;
    r0 = r0 < NN ? r0 : NN - 1;
    r1 = r1 < NN ? r1 : NN - 1;
    r2 = r2 < NN ? r2 : NN - 1;

#pragma unroll
    for (int ks = 0; ks < DIM; ks += 32) {
        long kbyte = (long)(ks + lk * 8) * 2;
        half8 a0 = *reinterpret_cast<const half8*>(xb + (long)r0 * 512 + kbyte);
        half8 a1 = *reinterpret_cast<const half8*>(xb + (long)r1 * 512 + kbyte);
        half8 a2 = *reinterpret_cast<const half8*>(xb + (long)r2 * 512 + kbyte);
#pragma unroll
        for (int fn = 0; fn < 16; ++fn) {
            int n = fn * 16 + lrow;
            int off = ((n << 9) + (int)kbyte) ^ ((n & 7) << 4);
            half8 b = *reinterpret_cast<const half8*>(&wl[off]);
            acc[0][fn] = __builtin_amdgcn_mfma_f32_16x16x32_f16(a0, b, acc[0][fn], 0, 0, 0);
            acc[1][fn] = __builtin_amdgcn_mfma_f32_16x16x32_f16(a1, b, acc[1][fn], 0, 0, 0);
            acc[2][fn] = __builtin_amdgcn_mfma_f32_16x16x32_f16(a2, b, acc[2][fn], 0, 0, 0);
        }
    }

    __fp16* yh = reinterpret_cast<__fp16*>(y);
#pragma unroll
    for (int m = 0; m < 3; ++m) {
        int rbase = wrow + m * 16 + lk * 4;
#pragma unroll
        for (int fn = 0; fn < 16; ++fn) {
            int colc = fn * 16 + lrow;
#pragma unroll
            for (int r = 0; r < 4; ++r) {
                int row = rbase + r;
                if (row < NN) yh[(long)row * DIM + colc] = (__fp16)acc[m][fn][r];
            }
        }
    }
}

// ---------------- per-graph sum pooling (graph_ids sorted) ----------------
__device__ inline int lbound(const int* __restrict__ a, int n, int v) {
    int lo = 0, hi = n;
    while (lo < hi) {
        int m = (lo + hi) >> 1;
        if (a[m] < v) lo = m + 1; else hi = m;
    }
    return lo;
}

__global__ __launch_bounds__(256) void k_pool(const ushort* __restrict__ h,
                                              const int* __restrict__ gids,
                                              float* __restrict__ out) {
    int g = blockIdx.x;
    int t = threadIdx.x;
    int lo = lbound(gids, NN, g);
    int hi = lbound(gids, NN, g + 1);
    const __fp16* hh = reinterpret_cast<const __fp16*>(h);
    float acc = 0.f;
    for (int nd = lo; nd < hi; ++nd) acc += (float)hh[(long)nd * DIM + t];
    out[(long)g * DIM + t] = acc;
}

extern "C" void kernel_launch(void* const* d_in, const int* in_sizes, int n_in,
                              void* d_out, int out_size, void* d_ws, size_t ws_size,
                              hipStream_t stream) {
    const int* feature = (const int*)d_in[0];
    const int* src = (const int*)d_in[1];
    const int* dst = (const int*)d_in[2];
    const int* gids = (const int*)d_in[3];
    const float* emb = (const float*)d_in[4];
    const float* W1 = (const float*)d_in[5];
    const float* W2 = (const float*)d_in[6];
    float* out = (float*)d_out;

    // workspace carve (all 16B aligned)
    char* p = (char*)d_ws;
    ushort* hA = (ushort*)p;            p += (size_t)NN * DIM * 2;
    ushort* hB = (ushort*)p;            p += (size_t)NN * DIM * 2;
    ushort* Wt1 = (ushort*)p;           p += (size_t)DIM * DIM * 2;
    ushort* Wt2 = (ushort*)p;           p += (size_t)DIM * DIM * 2;
    float* onorm = (float*)p;           p += (size_t)NN * 4;
    float* inorm = (float*)p;           p += (size_t)NN * 4;
    int* rowptr = (int*)p;              p += (size_t)(NN + 4) * 4;
    int* colidx = (int*)p;              p += (size_t)NE * 4;
    int* outd = (int*)p;                p += (size_t)NN * 4;
    int* ind = (int*)p;                 p += (size_t)NN * 4;
    int* locex = (int*)p;               p += (size_t)NN * 4;
    int* partials = (int*)p;            p += (size_t)128 * 4;
    ushort* slots = (ushort*)p;         p += (size_t)NE * 2;

    hipMemsetAsync(outd, 0, (size_t)2 * NN * 4, stream);  // outd | ind contiguous

    k_count<<<2048, 256, 0, stream>>>(src, dst, outd, ind, slots);
    k_scan1<<<NBLK, SCAN_B, 0, stream>>>(ind, locex, partials);
    k_scan2<<<1, 128, 0, stream>>>(partials, rowptr + NN);
    k_scan3<<<NBLK, SCAN_B, 0, stream>>>(locex, partials, outd, ind, rowptr, onorm, inorm);
    // fused: scatter | weight transpose | embed (+onorm prescale) — all ready after scan3
    k_scatter_wconv_embed<<<SCAT_BLK + WCONV_BLK + EMB_BLK, 256, 0, stream>>>(
        src, dst, rowptr, slots, colidx, W1, W2, Wt1, Wt2, feature, emb, onorm, hA);

    const int aggGrid = (NN * 64 + 255) / 256;
    const int gemmGrid = (NN + 383) / 384;
    // layer 0 (no W): hB = relu(agg(hA) * inorm) * onorm
    k_agg<0><<<aggGrid, 256, 0, stream>>>(rowptr, colidx, hA, inorm, onorm, hB);
    // layer 1: hA = hB @ W1 ; hB = relu(agg(hA) * inorm) * onorm
    k_gemm<<<gemmGrid, 512, 0, stream>>>(hB, Wt1, hA);
    k_agg<0><<<aggGrid, 256, 0, stream>>>(rowptr, colidx, hA, inorm, onorm, hB);
    // layer 2: hA = hB @ W2 ; hB = agg(hA) * inorm
    k_gemm<<<gemmGrid, 512, 0, stream>>>(hB, Wt2, hA);
    k_agg<1><<<aggGrid, 256, 0, stream>>>(rowptr, colidx, hA, inorm, onorm, hB);
    // pool per graph
    k_pool<<<NG, 256, 0, stream>>>(hB, gids, out);
}

// Round 9
// 637.640 us; speedup vs baseline: 1.0419x; 1.0419x over previous
//
#include <hip/hip_runtime.h>
#include <hip/hip_fp16.h>

#define NN 100000
#define NE 1600000
#define NG 2000
#define DIM 256
#define NF 4
#define SCAN_B 1024
#define NBLK ((NN + SCAN_B - 1) / SCAN_B)   // 98
#define SCAT_BLK 2048
#define WCONV_BLK 128
#define EMB_BLK ((NN * 64) / 256)           // 25000

using half8 = __attribute__((ext_vector_type(8))) _Float16;
using f32x4 = __attribute__((ext_vector_type(4))) float;

__device__ inline float4 h4_to_f4(uint2 v) {
    __half2 a = *reinterpret_cast<__half2*>(&v.x);
    __half2 b = *reinterpret_cast<__half2*>(&v.y);
    float2 fa = __half22float2(a);
    float2 fb = __half22float2(b);
    return make_float4(fa.x, fa.y, fb.x, fb.y);
}

__device__ inline uint2 f4_to_h4(float4 r) {
    __half2 a = __floats2half2_rn(r.x, r.y);
    __half2 b = __floats2half2_rn(r.z, r.w);
    uint2 o;
    o.x = *reinterpret_cast<uint*>(&a);
    o.y = *reinterpret_cast<uint*>(&b);
    return o;
}

__device__ inline void add8(float4& a0, float4& a1, uint4 u) {
    uint2 lo2; lo2.x = u.x; lo2.y = u.y;
    uint2 hi2; hi2.x = u.z; hi2.y = u.w;
    float4 lo = h4_to_f4(lo2);
    float4 hi = h4_to_f4(hi2);
    a0.x += lo.x; a0.y += lo.y; a0.z += lo.z; a0.w += lo.w;
    a1.x += hi.x; a1.y += hi.y; a1.z += hi.z; a1.w += hi.w;
}

// ---------------- degree counting + slot capture ----------------
__global__ void k_count(const int* __restrict__ src, const int* __restrict__ dst,
                        int* __restrict__ outd, int* __restrict__ ind,
                        ushort* __restrict__ slots) {
    int i = blockIdx.x * blockDim.x + threadIdx.x;
    int stride = gridDim.x * blockDim.x;
    for (; i < NE; i += stride) {
        atomicAdd(&outd[src[i]], 1);
        int s = atomicAdd(&ind[dst[i]], 1);
        slots[i] = (ushort)s;
    }
}

// ---------------- multi-block exclusive scan of in-degrees ----------------
__global__ __launch_bounds__(1024) void k_scan1(const int* __restrict__ deg,
                                                int* __restrict__ locex,
                                                int* __restrict__ partials) {
    __shared__ int sm[SCAN_B];
    int t = threadIdx.x;
    int i = blockIdx.x * SCAN_B + t;
    int v = (i < NN) ? deg[i] : 0;
    sm[t] = v;
    __syncthreads();
    for (int off = 1; off < SCAN_B; off <<= 1) {
        int u = (t >= off) ? sm[t - off] : 0;
        __syncthreads();
        sm[t] += u;
        __syncthreads();
    }
    if (i < NN) locex[i] = sm[t] - v;
    if (t == SCAN_B - 1) partials[blockIdx.x] = sm[t];
}

__global__ __launch_bounds__(128) void k_scan2(int* __restrict__ partials,
                                               int* __restrict__ rowptr_last) {
    __shared__ int sm[128];
    int t = threadIdx.x;
    int v = (t < NBLK) ? partials[t] : 0;
    sm[t] = v;
    __syncthreads();
    for (int off = 1; off < 128; off <<= 1) {
        int u = (t >= off) ? sm[t - off] : 0;
        __syncthreads();
        sm[t] += u;
        __syncthreads();
    }
    if (t < NBLK) partials[t] = sm[t] - v;
    if (t == 127) *rowptr_last = sm[127];
}

// phase 3: rowptr = locex + block offset; norms fused (per-node pass)
__global__ __launch_bounds__(1024) void k_scan3(const int* __restrict__ locex,
                                                const int* __restrict__ partials,
                                                const int* __restrict__ outd,
                                                const int* __restrict__ ind,
                                                int* __restrict__ rowptr,
                                                float* __restrict__ onorm,
                                                float* __restrict__ inorm) {
    int i = blockIdx.x * SCAN_B + threadIdx.x;
    if (i < NN) {
        rowptr[i] = locex[i] + partials[blockIdx.x];
        int od = outd[i];
        int id = ind[i];
        onorm[i] = od > 0 ? rsqrtf((float)od) : 0.f;
        inorm[i] = id > 0 ? rsqrtf((float)id) : 0.f;
    }
}

// -------- FUSED: atomic-free scatter | W1->Wt1 fp16 | embedding sum + onorm prescale ------
__global__ void k_scatter_wconv_embed(const int* __restrict__ src, const int* __restrict__ dst,
                                      const int* __restrict__ rowptr,
                                      const ushort* __restrict__ slots,
                                      int* __restrict__ col,
                                      const float* __restrict__ W1,
                                      ushort* __restrict__ Wt1,
                                      const int* __restrict__ feat, const float* __restrict__ emb,
                                      const float* __restrict__ onorm, ushort* __restrict__ h) {
    int tid = threadIdx.x;
    if (blockIdx.x < SCAT_BLK) {
        int i = blockIdx.x * 256 + tid;
        const int stride = SCAT_BLK * 256;
        for (; i < NE; i += stride) {
            int d = dst[i];
            col[rowptr[d] + (int)slots[i]] = src[i];
        }
    } else if (blockIdx.x < SCAT_BLK + WCONV_BLK) {
        int idx = (blockIdx.x - SCAT_BLK) * 512 + tid * 2;  // 2 elems/thread, 65536 total
        int k0 = idx >> 8;
        int n0 = idx & 255;
        reinterpret_cast<__fp16*>(Wt1)[n0 * DIM + k0] = (__fp16)W1[idx];
        int idx1 = idx + 1;
        int k1 = idx1 >> 8;
        int n1 = idx1 & 255;
        reinterpret_cast<__fp16*>(Wt1)[n1 * DIM + k1] = (__fp16)W1[idx1];
    } else {
        int idx = (blockIdx.x - SCAT_BLK - WCONV_BLK) * 256 + tid;  // NN*64 total
        int node = idx >> 6;
        int g = idx & 63;
        if (node >= NN) return;
        const int4 f = *reinterpret_cast<const int4*>(feat + node * 4);
        const float4* emb4 = reinterpret_cast<const float4*>(emb);
        float4 a = emb4[(long)f.x * 64 + g];
        float4 b = emb4[(long)f.y * 64 + g];
        float4 c = emb4[(long)f.z * 64 + g];
        float4 d = emb4[(long)f.w * 64 + g];
        float sc = onorm[node];
        float4 r;
        r.x = (a.x + b.x + c.x + d.x) * sc;
        r.y = (a.y + b.y + c.y + d.y) * sc;
        r.z = (a.z + b.z + c.z + d.z) * sc;
        r.w = (a.w + b.w + c.w + d.w) * sc;
        reinterpret_cast<uint2*>(h)[(long)node * 64 + g] = f4_to_h4(r);
    }
}

// ---------------- aggregation: one wave per dst node ----------------
// MODE 0: hout = relu(acc * inorm) * onorm ; MODE 1: hout = acc * inorm
template <int MODE>
__global__ void k_agg(const int* __restrict__ rowptr, const int* __restrict__ col,
                      const ushort* __restrict__ hin, const float* __restrict__ inorm,
                      const float* __restrict__ onorm, ushort* __restrict__ hout) {
    int wid = (blockIdx.x * blockDim.x + threadIdx.x) >> 6;
    int lane = threadIdx.x & 63;
    if (wid >= NN) return;
    int half = lane >> 5;
    int l32 = lane & 31;
    int e0 = rowptr[wid];
    int e1 = rowptr[wid + 1];
    const uint4* hin4 = reinterpret_cast<const uint4*>(hin);
    float4 aA0 = {0,0,0,0}, aA1 = {0,0,0,0};
    float4 aB0 = {0,0,0,0}, aB1 = {0,0,0,0};
    int e = e0;
    for (; e + 8 <= e1; e += 8) {
        int s0 = col[e + 0 + half];
        int s1 = col[e + 2 + half];
        int s2 = col[e + 4 + half];
        int s3 = col[e + 6 + half];
        uint4 u0 = hin4[(long)s0 * 32 + l32];
        uint4 u1 = hin4[(long)s1 * 32 + l32];
        uint4 u2 = hin4[(long)s2 * 32 + l32];
        uint4 u3 = hin4[(long)s3 * 32 + l32];
        add8(aA0, aA1, u0);
        add8(aB0, aB1, u1);
        add8(aA0, aA1, u2);
        add8(aB0, aB1, u3);
    }
    for (; e < e1; e += 2) {
        int idx = e + half;
        if (idx < e1) {
            int s = col[idx];
            uint4 u = hin4[(long)s * 32 + l32];
            add8(aA0, aA1, u);
        }
    }
    float f[8];
    f[0] = aA0.x + aB0.x; f[1] = aA0.y + aB0.y; f[2] = aA0.z + aB0.z; f[3] = aA0.w + aB0.w;
    f[4] = aA1.x + aB1.x; f[5] = aA1.y + aB1.y; f[6] = aA1.z + aB1.z; f[7] = aA1.w + aB1.w;
#pragma unroll
    for (int j = 0; j < 8; ++j) f[j] += __shfl_xor(f[j], 32);

    float sc = inorm[wid];
    float4 r0, r1;
    if (MODE == 0) {
        float on = onorm[wid];
        r0.x = fmaxf(f[0] * sc, 0.f) * on;
        r0.y = fmaxf(f[1] * sc, 0.f) * on;
        r0.z = fmaxf(f[2] * sc, 0.f) * on;
        r0.w = fmaxf(f[3] * sc, 0.f) * on;
        r1.x = fmaxf(f[4] * sc, 0.f) * on;
        r1.y = fmaxf(f[5] * sc, 0.f) * on;
        r1.z = fmaxf(f[6] * sc, 0.f) * on;
        r1.w = fmaxf(f[7] * sc, 0.f) * on;
    } else {
        r0.x = f[0] * sc; r0.y = f[1] * sc; r0.z = f[2] * sc; r0.w = f[3] * sc;
        r1.x = f[4] * sc; r1.y = f[5] * sc; r1.z = f[6] * sc; r1.w = f[7] * sc;
    }
    if (half == 0) {
        uint2 lo = f4_to_h4(r0);
        uint2 hi = f4_to_h4(r1);
        uint4 o; o.x = lo.x; o.y = lo.y; o.z = hi.x; o.w = hi.y;
        reinterpret_cast<uint4*>(hout)[(long)wid * 32 + l32] = o;
    }
}

// ---------------- MFMA GEMM: y[NN,256] = x[NN,256] @ W[256,256] ----------------
__global__ __launch_bounds__(512, 2) void k_gemm(const ushort* __restrict__ x,
                                                 const ushort* __restrict__ Wt,
                                                 ushort* __restrict__ y) {
    __shared__ char wl[131072];
    int tid = threadIdx.x;
    const uint4* Wt4 = reinterpret_cast<const uint4*>(Wt);
#pragma unroll
    for (int it = 0; it < 16; ++it) {
        int chunk = it * 512 + tid;      // 0..8191 16B-chunks
        int n = chunk >> 5;              // row 0..255
        int c16 = chunk & 31;
        uint4 v = Wt4[chunk];
        int off = ((n << 9) + (c16 << 4)) ^ ((n & 7) << 4);
        *reinterpret_cast<uint4*>(&wl[off]) = v;
    }
    __syncthreads();

    int w = tid >> 6;
    int l = tid & 63;
    int wrow = blockIdx.x * 384 + w * 48;
    int lrow = l & 15;
    int lk = l >> 4;

    f32x4 acc[3][16];
#pragma unroll
    for (int m = 0; m < 3; ++m)
#pragma unroll
        for (int n = 0; n < 16; ++n) acc[m][n] = {0.f, 0.f, 0.f, 0.f};

    const char* xb = reinterpret_cast<const char*>(x);
    int r0 = wrow + lrow;
    int r1 = r0 + 16;
    int r2 = r0 + 32;
    r0 = r0 < NN ? r0 : NN - 1;
    r1 = r1 < NN ? r1 : NN - 1;
    r2 = r2 < NN ? r2 : NN - 1;

#pragma unroll
    for (int ks = 0; ks < DIM; ks += 32) {
        long kbyte = (long)(ks + lk * 8) * 2;
        half8 a0 = *reinterpret_cast<const half8*>(xb + (long)r0 * 512 + kbyte);
        half8 a1 = *reinterpret_cast<const half8*>(xb + (long)r1 * 512 + kbyte);
        half8 a2 = *reinterpret_cast<const half8*>(xb + (long)r2 * 512 + kbyte);
#pragma unroll
        for (int fn = 0; fn < 16; ++fn) {
            int n = fn * 16 + lrow;
            int off = ((n << 9) + (int)kbyte) ^ ((n & 7) << 4);
            half8 b = *reinterpret_cast<const half8*>(&wl[off]);
            acc[0][fn] = __builtin_amdgcn_mfma_f32_16x16x32_f16(a0, b, acc[0][fn], 0, 0, 0);
            acc[1][fn] = __builtin_amdgcn_mfma_f32_16x16x32_f16(a1, b, acc[1][fn], 0, 0, 0);
            acc[2][fn] = __builtin_amdgcn_mfma_f32_16x16x32_f16(a2, b, acc[2][fn], 0, 0, 0);
        }
    }

    __fp16* yh = reinterpret_cast<__fp16*>(y);
#pragma unroll
    for (int m = 0; m < 3; ++m) {
        int rbase = wrow + m * 16 + lk * 4;
#pragma unroll
        for (int fn = 0; fn < 16; ++fn) {
            int colc = fn * 16 + lrow;
#pragma unroll
            for (int r = 0; r < 4; ++r) {
                int row = rbase + r;
                if (row < NN) yh[(long)row * DIM + colc] = (__fp16)acc[m][fn][r];
            }
        }
    }
}

// ---------------- per-graph sum pooling (graph_ids sorted) -> P fp32 ----------------
__device__ inline int lbound(const int* __restrict__ a, int n, int v) {
    int lo = 0, hi = n;
    while (lo < hi) {
        int m = (lo + hi) >> 1;
        if (a[m] < v) lo = m + 1; else hi = m;
    }
    return lo;
}

__global__ __launch_bounds__(256) void k_pool(const ushort* __restrict__ h,
                                              const int* __restrict__ gids,
                                              float* __restrict__ P) {
    int g = blockIdx.x;
    int t = threadIdx.x;
    int lo = lbound(gids, NN, g);
    int hi = lbound(gids, NN, g + 1);
    const __fp16* hh = reinterpret_cast<const __fp16*>(h);
    float acc = 0.f;
    for (int nd = lo; nd < hi; ++nd) acc += (float)hh[(long)nd * DIM + t];
    P[(long)g * DIM + t] = acc;
}

// ---------------- mini-GEMM: out[NG,256] = P[NG,256] @ W2[256,256] (fp32) ----------------
// Linearity: pool(inorm*agg(h')) @ W2 == pool(inorm*agg(h' @ W2)).
// block = 256 threads handles 8 rows; thread t owns column t for all 8 rows.
__global__ __launch_bounds__(256) void k_pgemm(const float* __restrict__ P,
                                               const float* __restrict__ W2,
                                               float* __restrict__ out) {
    __shared__ float Pl[8][DIM];
    int t = threadIdx.x;
    int rbase = blockIdx.x * 8;
    // stage 8 P rows (8 KB)
#pragma unroll
    for (int r = 0; r < 8; ++r) Pl[r][t] = P[(long)(rbase + r) * DIM + t];
    __syncthreads();
    float acc[8];
#pragma unroll
    for (int r = 0; r < 8; ++r) acc[r] = 0.f;
    for (int k = 0; k < DIM; ++k) {
        float w = W2[(long)k * DIM + t];   // coalesced; W2 is L2-resident
#pragma unroll
        for (int r = 0; r < 8; ++r) acc[r] += Pl[r][k] * w;
    }
#pragma unroll
    for (int r = 0; r < 8; ++r) out[(long)(rbase + r) * DIM + t] = acc[r];
}

extern "C" void kernel_launch(void* const* d_in, const int* in_sizes, int n_in,
                              void* d_out, int out_size, void* d_ws, size_t ws_size,
                              hipStream_t stream) {
    const int* feature = (const int*)d_in[0];
    const int* src = (const int*)d_in[1];
    const int* dst = (const int*)d_in[2];
    const int* gids = (const int*)d_in[3];
    const float* emb = (const float*)d_in[4];
    const float* W1 = (const float*)d_in[5];
    const float* W2 = (const float*)d_in[6];
    float* out = (float*)d_out;

    // workspace carve (all 16B aligned)
    char* p = (char*)d_ws;
    ushort* hA = (ushort*)p;            p += (size_t)NN * DIM * 2;
    ushort* hB = (ushort*)p;            p += (size_t)NN * DIM * 2;
    ushort* Wt1 = (ushort*)p;           p += (size_t)DIM * DIM * 2;
    float* onorm = (float*)p;           p += (size_t)NN * 4;
    float* inorm = (float*)p;           p += (size_t)NN * 4;
    int* rowptr = (int*)p;              p += (size_t)(NN + 4) * 4;
    int* colidx = (int*)p;              p += (size_t)NE * 4;
    int* outd = (int*)p;                p += (size_t)NN * 4;
    int* ind = (int*)p;                 p += (size_t)NN * 4;
    int* locex = (int*)p;               p += (size_t)NN * 4;
    int* partials = (int*)p;            p += (size_t)128 * 4;
    ushort* slots = (ushort*)p;         p += (size_t)NE * 2;
    float* Pbuf = (float*)p;            p += (size_t)NG * DIM * 4;

    hipMemsetAsync(outd, 0, (size_t)2 * NN * 4, stream);  // outd | ind contiguous

    k_count<<<2048, 256, 0, stream>>>(src, dst, outd, ind, slots);
    k_scan1<<<NBLK, SCAN_B, 0, stream>>>(ind, locex, partials);
    k_scan2<<<1, 128, 0, stream>>>(partials, rowptr + NN);
    k_scan3<<<NBLK, SCAN_B, 0, stream>>>(locex, partials, outd, ind, rowptr, onorm, inorm);
    // fused: scatter | W1 transpose->fp16 | embed (+onorm prescale)
    k_scatter_wconv_embed<<<SCAT_BLK + WCONV_BLK + EMB_BLK, 256, 0, stream>>>(
        src, dst, rowptr, slots, colidx, W1, Wt1, feature, emb, onorm, hA);

    const int aggGrid = (NN * 64 + 255) / 256;
    const int gemmGrid = (NN + 383) / 384;
    // layer 0 (no W): hB = relu(agg(hA) * inorm) * onorm
    k_agg<0><<<aggGrid, 256, 0, stream>>>(rowptr, colidx, hA, inorm, onorm, hB);
    // layer 1: hA = hB @ W1 ; hB = relu(agg(hA) * inorm) * onorm
    k_gemm<<<gemmGrid, 512, 0, stream>>>(hB, Wt1, hA);
    k_agg<0><<<aggGrid, 256, 0, stream>>>(rowptr, colidx, hA, inorm, onorm, hB);
    // layer 2 (W2 hoisted past agg+pool by linearity): hA = agg(hB) * inorm
    k_agg<1><<<aggGrid, 256, 0, stream>>>(rowptr, colidx, hB, inorm, onorm, hA);
    // P = pool(hA) ; out = P @ W2
    k_pool<<<NG, 256, 0, stream>>>(hA, gids, Pbuf);
    k_pgemm<<<NG / 8, 256, 0, stream>>>(Pbuf, W2, out);
}

// Round 10
// 577.466 us; speedup vs baseline: 1.1504x; 1.1042x over previous
//
#include <hip/hip_runtime.h>
#include <hip/hip_fp16.h>

#define NN 100000
#define NE 1600000
#define NG 2000
#define DIM 256
#define NF 4
#define NBUK 196                 // ceil(NN / 512)
#define BSH 9                    // 512 nodes per bucket
#define BNODES 512
#define CHUNKS 512               // L1 scatter blocks
#define CHUNK_E (NE / CHUNKS)    // 3125 edges per chunk
#define OUTD_BLK 1024
#define BH_BLK CHUNKS            // bucket-hist blocks in K1
#define WCONV_BLK 128
#define EMB_BLK ((NN * 64) / 256)  // 25000
#define COLBUF_CAP 12288         // LDS col staging (bucket n ~8163 +- 90)

using half8 = __attribute__((ext_vector_type(8))) _Float16;
using f32x4 = __attribute__((ext_vector_type(4))) float;

__device__ inline float4 h4_to_f4(uint2 v) {
    __half2 a = *reinterpret_cast<__half2*>(&v.x);
    __half2 b = *reinterpret_cast<__half2*>(&v.y);
    float2 fa = __half22float2(a);
    float2 fb = __half22float2(b);
    return make_float4(fa.x, fa.y, fb.x, fb.y);
}

__device__ inline uint2 f4_to_h4(float4 r) {
    __half2 a = __floats2half2_rn(r.x, r.y);
    __half2 b = __floats2half2_rn(r.z, r.w);
    uint2 o;
    o.x = *reinterpret_cast<uint*>(&a);
    o.y = *reinterpret_cast<uint*>(&b);
    return o;
}

__device__ inline void add8(float4& a0, float4& a1, uint4 u) {
    uint2 lo2; lo2.x = u.x; lo2.y = u.y;
    uint2 hi2; hi2.x = u.z; hi2.y = u.w;
    float4 lo = h4_to_f4(lo2);
    float4 hi = h4_to_f4(hi2);
    a0.x += lo.x; a0.y += lo.y; a0.z += lo.z; a0.w += lo.w;
    a1.x += hi.x; a1.y += hi.y; a1.z += hi.z; a1.w += hi.w;
}

// ---- K1 FUSED: outd histogram | coarse bucket histogram (LDS-privatized) | W1->Wt1 ----
__global__ void k_hist(const int* __restrict__ src, const int* __restrict__ dst,
                       int* __restrict__ outd, int* __restrict__ bcnt,
                       const float* __restrict__ W1, ushort* __restrict__ Wt1) {
    int tid = threadIdx.x;
    if (blockIdx.x < OUTD_BLK) {
        int i = blockIdx.x * 256 + tid;
        const int stride = OUTD_BLK * 256;
        for (; i < NE; i += stride) atomicAdd(&outd[src[i]], 1);
    } else if (blockIdx.x < OUTD_BLK + BH_BLK) {
        __shared__ int h[NBUK];
        int cb = blockIdx.x - OUTD_BLK;
        int e0 = cb * CHUNK_E;
        if (tid < NBUK) h[tid] = 0;
        __syncthreads();
        for (int e = e0 + tid; e < e0 + CHUNK_E; e += 256)
            atomicAdd(&h[dst[e] >> BSH], 1);
        __syncthreads();
        if (tid < NBUK && h[tid] > 0) atomicAdd(&bcnt[tid], h[tid]);
    } else {
        int idx = (blockIdx.x - OUTD_BLK - BH_BLK) * 512 + tid * 2;  // 65536 total
        int k0 = idx >> 8, n0 = idx & 255;
        reinterpret_cast<__fp16*>(Wt1)[n0 * DIM + k0] = (__fp16)W1[idx];
        int idx1 = idx + 1;
        int k1 = idx1 >> 8, n1 = idx1 & 255;
        reinterpret_cast<__fp16*>(Wt1)[n1 * DIM + k1] = (__fp16)W1[idx1];
    }
}

// ---- K2: exclusive scan of bucket counts -> boff[0..NBUK], gcur init ----
__global__ __launch_bounds__(256) void k_bscan(const int* __restrict__ bcnt,
                                               int* __restrict__ boff,
                                               int* __restrict__ gcur) {
    __shared__ int sm[256];
    int t = threadIdx.x;
    int v = (t < NBUK) ? bcnt[t] : 0;
    sm[t] = v;
    __syncthreads();
    for (int off = 1; off < 256; off <<= 1) {
        int u = (t >= off) ? sm[t - off] : 0;
        __syncthreads();
        sm[t] += u;
        __syncthreads();
    }
    if (t < NBUK) {
        int ex = sm[t] - v;
        boff[t] = ex;
        gcur[t] = ex;
    }
    if (t == 255) boff[NBUK] = sm[255];
}

// ---- K3 FUSED: L1 bucket scatter of (dst,src) pairs | embed + onorm (reads outd) ----
__global__ void k_bscatter_embed(const int* __restrict__ src, const int* __restrict__ dst,
                                 int* __restrict__ gcur, uint2* __restrict__ pairs,
                                 const int* __restrict__ feat, const float* __restrict__ emb,
                                 const int* __restrict__ outd,
                                 float* __restrict__ onorm, ushort* __restrict__ h) {
    int tid = threadIdx.x;
    if (blockIdx.x < CHUNKS) {
        __shared__ int h1[NBUK];
        __shared__ int base1[NBUK];
        __shared__ int cur1[NBUK];
        int e0 = blockIdx.x * CHUNK_E;
        if (tid < NBUK) h1[tid] = 0;
        __syncthreads();
        for (int e = e0 + tid; e < e0 + CHUNK_E; e += 256)
            atomicAdd(&h1[dst[e] >> BSH], 1);
        __syncthreads();
        if (tid < NBUK) {
            int c = h1[tid];
            base1[tid] = (c > 0) ? atomicAdd(&gcur[tid], c) : 0;
            cur1[tid] = 0;
        }
        __syncthreads();
        for (int e = e0 + tid; e < e0 + CHUNK_E; e += 256) {
            int d = dst[e];
            int b = d >> BSH;
            int r = atomicAdd(&cur1[b], 1);
            uint2 pr;
            pr.x = (uint)d;
            pr.y = (uint)src[e];
            pairs[base1[b] + r] = pr;
        }
    } else {
        int idx = (blockIdx.x - CHUNKS) * 256 + tid;  // NN*64 total
        int node = idx >> 6;
        int g = idx & 63;
        if (node >= NN) return;
        int od = outd[node];
        float sc = od > 0 ? rsqrtf((float)od) : 0.f;
        if (g == 0) onorm[node] = sc;
        const int4 f = *reinterpret_cast<const int4*>(feat + node * 4);
        const float4* emb4 = reinterpret_cast<const float4*>(emb);
        float4 a = emb4[(long)f.x * 64 + g];
        float4 b = emb4[(long)f.y * 64 + g];
        float4 c = emb4[(long)f.z * 64 + g];
        float4 d = emb4[(long)f.w * 64 + g];
        float4 r;
        r.x = (a.x + b.x + c.x + d.x) * sc;
        r.y = (a.y + b.y + c.y + d.y) * sc;
        r.z = (a.z + b.z + c.z + d.z) * sc;
        r.w = (a.w + b.w + c.w + d.w) * sc;
        reinterpret_cast<uint2*>(h)[(long)node * 64 + g] = f4_to_h4(r);
    }
}

// ---- K4: per-bucket CSR finalize: LDS 512-bin hist + scan + LDS scatter -> col, rowptr, inorm
__global__ __launch_bounds__(1024) void k_bsort(const uint2* __restrict__ pairs,
                                                const int* __restrict__ boff,
                                                int* __restrict__ col,
                                                int* __restrict__ rowptr,
                                                float* __restrict__ inorm) {
    __shared__ int hist[BNODES];
    __shared__ int sc[BNODES];
    __shared__ int ex[BNODES];
    __shared__ int cur[BNODES];
    __shared__ int colbuf[COLBUF_CAP];
    int t = threadIdx.x;
    int b = blockIdx.x;
    int o0 = boff[b];
    int n = boff[b + 1] - o0;

    if (t < BNODES) hist[t] = 0;
    __syncthreads();
    for (int i = t; i < n; i += 1024) {
        uint2 p = pairs[o0 + i];
        atomicAdd(&hist[p.x & (BNODES - 1)], 1);
    }
    __syncthreads();
    // block scan (Hillis-Steele over 512 bins; all 1024 threads hit barriers)
    int v = (t < BNODES) ? hist[t] : 0;
    if (t < BNODES) sc[t] = v;
    __syncthreads();
    for (int off = 1; off < BNODES; off <<= 1) {
        int u = (t < BNODES && t >= off) ? sc[t - off] : 0;
        __syncthreads();
        if (t < BNODES) sc[t] += u;
        __syncthreads();
    }
    if (t < BNODES) {
        ex[t] = sc[t] - v;
        cur[t] = 0;
        int node = (b << BSH) + t;
        if (node < NN) {
            rowptr[node] = o0 + ex[t];
            inorm[node] = v > 0 ? rsqrtf((float)v) : 0.f;
        }
    }
    if (b == NBUK - 1 && t == 0) rowptr[NN] = NE;
    __syncthreads();

    if (n <= COLBUF_CAP) {
        for (int i = t; i < n; i += 1024) {
            uint2 p = pairs[o0 + i];
            int ld = p.x & (BNODES - 1);
            int r = atomicAdd(&cur[ld], 1);
            colbuf[ex[ld] + r] = (int)p.y;
        }
        __syncthreads();
        for (int i = t; i < n; i += 1024) col[o0 + i] = colbuf[i];
    } else {  // statistically unreachable fallback
        for (int i = t; i < n; i += 1024) {
            uint2 p = pairs[o0 + i];
            int ld = p.x & (BNODES - 1);
            int r = atomicAdd(&cur[ld], 1);
            col[o0 + ex[ld] + r] = (int)p.y;
        }
    }
}

// ---------------- aggregation: one wave per dst node ----------------
// MODE 0: hout = relu(acc * inorm) * onorm ; MODE 1: hout = acc * inorm
template <int MODE>
__global__ void k_agg(const int* __restrict__ rowptr, const int* __restrict__ col,
                      const ushort* __restrict__ hin, const float* __restrict__ inorm,
                      const float* __restrict__ onorm, ushort* __restrict__ hout) {
    int wid = (blockIdx.x * blockDim.x + threadIdx.x) >> 6;
    int lane = threadIdx.x & 63;
    if (wid >= NN) return;
    int half = lane >> 5;
    int l32 = lane & 31;
    int e0 = rowptr[wid];
    int e1 = rowptr[wid + 1];
    const uint4* hin4 = reinterpret_cast<const uint4*>(hin);
    float4 aA0 = {0,0,0,0}, aA1 = {0,0,0,0};
    float4 aB0 = {0,0,0,0}, aB1 = {0,0,0,0};
    int e = e0;
    for (; e + 8 <= e1; e += 8) {
        int s0 = col[e + 0 + half];
        int s1 = col[e + 2 + half];
        int s2 = col[e + 4 + half];
        int s3 = col[e + 6 + half];
        uint4 u0 = hin4[(long)s0 * 32 + l32];
        uint4 u1 = hin4[(long)s1 * 32 + l32];
        uint4 u2 = hin4[(long)s2 * 32 + l32];
        uint4 u3 = hin4[(long)s3 * 32 + l32];
        add8(aA0, aA1, u0);
        add8(aB0, aB1, u1);
        add8(aA0, aA1, u2);
        add8(aB0, aB1, u3);
    }
    for (; e < e1; e += 2) {
        int idx = e + half;
        if (idx < e1) {
            int s = col[idx];
            uint4 u = hin4[(long)s * 32 + l32];
            add8(aA0, aA1, u);
        }
    }
    float f[8];
    f[0] = aA0.x + aB0.x; f[1] = aA0.y + aB0.y; f[2] = aA0.z + aB0.z; f[3] = aA0.w + aB0.w;
    f[4] = aA1.x + aB1.x; f[5] = aA1.y + aB1.y; f[6] = aA1.z + aB1.z; f[7] = aA1.w + aB1.w;
#pragma unroll
    for (int j = 0; j < 8; ++j) f[j] += __shfl_xor(f[j], 32);

    float scn = inorm[wid];
    float4 r0, r1;
    if (MODE == 0) {
        float on = onorm[wid];
        r0.x = fmaxf(f[0] * scn, 0.f) * on;
        r0.y = fmaxf(f[1] * scn, 0.f) * on;
        r0.z = fmaxf(f[2] * scn, 0.f) * on;
        r0.w = fmaxf(f[3] * scn, 0.f) * on;
        r1.x = fmaxf(f[4] * scn, 0.f) * on;
        r1.y = fmaxf(f[5] * scn, 0.f) * on;
        r1.z = fmaxf(f[6] * scn, 0.f) * on;
        r1.w = fmaxf(f[7] * scn, 0.f) * on;
    } else {
        r0.x = f[0] * scn; r0.y = f[1] * scn; r0.z = f[2] * scn; r0.w = f[3] * scn;
        r1.x = f[4] * scn; r1.y = f[5] * scn; r1.z = f[6] * scn; r1.w = f[7] * scn;
    }
    if (half == 0) {
        uint2 lo = f4_to_h4(r0);
        uint2 hi = f4_to_h4(r1);
        uint4 o; o.x = lo.x; o.y = lo.y; o.z = hi.x; o.w = hi.y;
        reinterpret_cast<uint4*>(hout)[(long)wid * 32 + l32] = o;
    }
}

// ---------------- MFMA GEMM: y[NN,256] = x[NN,256] @ W[256,256] ----------------
__global__ __launch_bounds__(512, 2) void k_gemm(const ushort* __restrict__ x,
                                                 const ushort* __restrict__ Wt,
                                                 ushort* __restrict__ y) {
    __shared__ char wl[131072];
    int tid = threadIdx.x;
    const uint4* Wt4 = reinterpret_cast<const uint4*>(Wt);
#pragma unroll
    for (int it = 0; it < 16; ++it) {
        int chunk = it * 512 + tid;      // 0..8191 16B-chunks
        int n = chunk >> 5;              // row 0..255
        int c16 = chunk & 31;
        uint4 v = Wt4[chunk];
        int off = ((n << 9) + (c16 << 4)) ^ ((n & 7) << 4);
        *reinterpret_cast<uint4*>(&wl[off]) = v;
    }
    __syncthreads();

    int w = tid >> 6;
    int l = tid & 63;
    int wrow = blockIdx.x * 384 + w * 48;
    int lrow = l & 15;
    int lk = l >> 4;

    f32x4 acc[3][16];
#pragma unroll
    for (int m = 0; m < 3; ++m)
#pragma unroll
        for (int n = 0; n < 16; ++n) acc[m][n] = {0.f, 0.f, 0.f, 0.f};

    const char* xb = reinterpret_cast<const char*>(x);
    int r0 = wrow + lrow;
    int r1 = r0 + 16;
    int r2 = r0 + 32;
    r0 = r0 < NN ? r0 : NN - 1;
    r1 = r1 < NN ? r1 : NN - 1;
    r2 = r2 < NN ? r2 : NN - 1;

#pragma unroll
    for (int ks = 0; ks < DIM; ks += 32) {
        long kbyte = (long)(ks + lk * 8) * 2;
        half8 a0 = *reinterpret_cast<const half8*>(xb + (long)r0 * 512 + kbyte);
        half8 a1 = *reinterpret_cast<const half8*>(xb + (long)r1 * 512 + kbyte);
        half8 a2 = *reinterpret_cast<const half8*>(xb + (long)r2 * 512 + kbyte);
#pragma unroll
        for (int fn = 0; fn < 16; ++fn) {
            int n = fn * 16 + lrow;
            int off = ((n << 9) + (int)kbyte) ^ ((n & 7) << 4);
            half8 bb = *reinterpret_cast<const half8*>(&wl[off]);
            acc[0][fn] = __builtin_amdgcn_mfma_f32_16x16x32_f16(a0, bb, acc[0][fn], 0, 0, 0);
            acc[1][fn] = __builtin_amdgcn_mfma_f32_16x16x32_f16(a1, bb, acc[1][fn], 0, 0, 0);
            acc[2][fn] = __builtin_amdgcn_mfma_f32_16x16x32_f16(a2, bb, acc[2][fn], 0, 0, 0);
        }
    }

    __fp16* yh = reinterpret_cast<__fp16*>(y);
#pragma unroll
    for (int m = 0; m < 3; ++m) {
        int rbase = wrow + m * 16 + lk * 4;
#pragma unroll
        for (int fn = 0; fn < 16; ++fn) {
            int colc = fn * 16 + lrow;
#pragma unroll
            for (int r = 0; r < 4; ++r) {
                int row = rbase + r;
                if (row < NN) yh[(long)row * DIM + colc] = (__fp16)acc[m][fn][r];
            }
        }
    }
}

// ---------------- per-graph sum pooling (graph_ids sorted) -> P fp32 ----------------
__device__ inline int lbound(const int* __restrict__ a, int n, int v) {
    int lo = 0, hi = n;
    while (lo < hi) {
        int m = (lo + hi) >> 1;
        if (a[m] < v) lo = m + 1; else hi = m;
    }
    return lo;
}

__global__ __launch_bounds__(256) void k_pool(const ushort* __restrict__ h,
                                              const int* __restrict__ gids,
                                              float* __restrict__ P) {
    int g = blockIdx.x;
    int t = threadIdx.x;
    int lo = lbound(gids, NN, g);
    int hi = lbound(gids, NN, g + 1);
    const __fp16* hh = reinterpret_cast<const __fp16*>(h);
    float acc = 0.f;
    for (int nd = lo; nd < hi; ++nd) acc += (float)hh[(long)nd * DIM + t];
    P[(long)g * DIM + t] = acc;
}

// ---------------- mini-GEMM: out[NG,256] = P[NG,256] @ W2[256,256] (fp32) ----------------
__global__ __launch_bounds__(256) void k_pgemm(const float* __restrict__ P,
                                               const float* __restrict__ W2,
                                               float* __restrict__ out) {
    __shared__ float Pl[8][DIM];
    int t = threadIdx.x;
    int rbase = blockIdx.x * 8;
#pragma unroll
    for (int r = 0; r < 8; ++r) Pl[r][t] = P[(long)(rbase + r) * DIM + t];
    __syncthreads();
    float acc[8];
#pragma unroll
    for (int r = 0; r < 8; ++r) acc[r] = 0.f;
    for (int k = 0; k < DIM; ++k) {
        float w = W2[(long)k * DIM + t];
#pragma unroll
        for (int r = 0; r < 8; ++r) acc[r] += Pl[r][k] * w;
    }
#pragma unroll
    for (int r = 0; r < 8; ++r) out[(long)(rbase + r) * DIM + t] = acc[r];
}

extern "C" void kernel_launch(void* const* d_in, const int* in_sizes, int n_in,
                              void* d_out, int out_size, void* d_ws, size_t ws_size,
                              hipStream_t stream) {
    const int* feature = (const int*)d_in[0];
    const int* src = (const int*)d_in[1];
    const int* dst = (const int*)d_in[2];
    const int* gids = (const int*)d_in[3];
    const float* emb = (const float*)d_in[4];
    const float* W1 = (const float*)d_in[5];
    const float* W2 = (const float*)d_in[6];
    float* out = (float*)d_out;

    // workspace carve (all 16B aligned)
    char* p = (char*)d_ws;
    ushort* hA = (ushort*)p;            p += (size_t)NN * DIM * 2;
    ushort* hB = (ushort*)p;            p += (size_t)NN * DIM * 2;
    ushort* Wt1 = (ushort*)p;           p += (size_t)DIM * DIM * 2;
    float* onorm = (float*)p;           p += (size_t)NN * 4;
    float* inorm = (float*)p;           p += (size_t)NN * 4;
    int* rowptr = (int*)p;              p += (size_t)(NN + 4) * 4;
    int* colidx = (int*)p;              p += (size_t)NE * 4;
    int* outd = (int*)p;                p += (size_t)NN * 4;       // zeroed
    int* bcnt = (int*)p;                p += (size_t)NBUK * 4;     // zeroed (adjacent)
    int* boff = (int*)p;                p += (size_t)(NBUK + 4) * 4;
    int* gcur = (int*)p;                p += (size_t)NBUK * 4;
    uint2* pairs = (uint2*)p;           p += (size_t)NE * 8;
    float* Pbuf = (float*)p;            p += (size_t)NG * DIM * 4;

    // zero outd + bcnt in one shot (adjacent)
    hipMemsetAsync(outd, 0, (size_t)NN * 4 + (size_t)NBUK * 4, stream);

    // K1: outd histogram | coarse bucket histogram | W1 -> Wt1
    k_hist<<<OUTD_BLK + BH_BLK + WCONV_BLK, 256, 0, stream>>>(src, dst, outd, bcnt, W1, Wt1);
    // K2: bucket offsets
    k_bscan<<<1, 256, 0, stream>>>(bcnt, boff, gcur);
    // K3: L1 scatter pairs | embed (+onorm)
    k_bscatter_embed<<<CHUNKS + EMB_BLK, 256, 0, stream>>>(src, dst, gcur, pairs,
                                                           feature, emb, outd, onorm, hA);
    // K4: per-bucket CSR finalize
    k_bsort<<<NBUK, 1024, 0, stream>>>(pairs, boff, colidx, rowptr, inorm);

    const int aggGrid = (NN * 64 + 255) / 256;
    const int gemmGrid = (NN + 383) / 384;
    // layer 0 (no W): hB = relu(agg(hA) * inorm) * onorm
    k_agg<0><<<aggGrid, 256, 0, stream>>>(rowptr, colidx, hA, inorm, onorm, hB);
    // layer 1: hA = hB @ W1 ; hB = relu(agg(hA) * inorm) * onorm
    k_gemm<<<gemmGrid, 512, 0, stream>>>(hB, Wt1, hA);
    k_agg<0><<<aggGrid, 256, 0, stream>>>(rowptr, colidx, hA, inorm, onorm, hB);
    // layer 2 (W2 hoisted past agg+pool by linearity): hA = agg(hB) * inorm
    k_agg<1><<<aggGrid, 256, 0, stream>>>(rowptr, colidx, hB, inorm, onorm, hA);
    // P = pool(hA) ; out = P @ W2
    k_pool<<<NG, 256, 0, stream>>>(hA, gids, Pbuf);
    k_pgemm<<<NG / 8, 256, 0, stream>>>(Pbuf, W2, out);
}

// Round 11
// 522.064 us; speedup vs baseline: 1.2725x; 1.1061x over previous
//
#include <hip/hip_runtime.h>
#include <hip/hip_fp16.h>

#define NN 100000
#define NE 1600000
#define NG 2000
#define DIM 256
#define NF 4
#define NBUK 196                 // ceil(NN / 512)
#define BSH 9                    // 512 nodes per bucket
#define BNODES 512
#define CHUNKS 512               // scatter blocks
#define CHUNK_E (NE / CHUNKS)    // 3125 edges per chunk
#define WCONV_BLK 128
#define PCAP 12288               // padded pair region per bucket (avg ~8163, 20+ sigma)
#define SCAP 12288               // padded src-low9 region per bucket
#define COLBUF_CAP 12288
#define EMB_BLK1K ((NN * 64) / 1024)   // 6250 (1024-thread embed blocks)

using half8 = __attribute__((ext_vector_type(8))) _Float16;
using f32x4 = __attribute__((ext_vector_type(4))) float;

__device__ inline float4 h4_to_f4(uint2 v) {
    __half2 a = *reinterpret_cast<__half2*>(&v.x);
    __half2 b = *reinterpret_cast<__half2*>(&v.y);
    float2 fa = __half22float2(a);
    float2 fb = __half22float2(b);
    return make_float4(fa.x, fa.y, fb.x, fb.y);
}

__device__ inline uint2 f4_to_h4(float4 r) {
    __half2 a = __floats2half2_rn(r.x, r.y);
    __half2 b = __floats2half2_rn(r.z, r.w);
    uint2 o;
    o.x = *reinterpret_cast<uint*>(&a);
    o.y = *reinterpret_cast<uint*>(&b);
    return o;
}

__device__ inline void add8(float4& a0, float4& a1, uint4 u) {
    uint2 lo2; lo2.x = u.x; lo2.y = u.y;
    uint2 hi2; hi2.x = u.z; hi2.y = u.w;
    float4 lo = h4_to_f4(lo2);
    float4 hi = h4_to_f4(hi2);
    a0.x += lo.x; a0.y += lo.y; a0.z += lo.z; a0.w += lo.w;
    a1.x += hi.x; a1.y += hi.y; a1.z += hi.z; a1.w += hi.w;
}

// ---- K1 FUSED: dual bucket scatter (pairs by dst-bucket, src-low9 by src-bucket) | wconv ----
// Padded regions (b*PCAP / b*SCAP) -> no pre-scan needed; only 196-counter global atomics.
__global__ void k_scatter2(const int* __restrict__ src, const int* __restrict__ dst,
                           int* __restrict__ pcnt, int* __restrict__ scnt,
                           uint* __restrict__ pbuf, ushort* __restrict__ sbuf,
                           const float* __restrict__ W1, ushort* __restrict__ Wt1) {
    int tid = threadIdx.x;
    if (blockIdx.x < CHUNKS) {
        __shared__ int h1[NBUK], b1[NBUK], c1[NBUK];
        __shared__ int h2[NBUK], b2[NBUK], c2[NBUK];
        int e0 = blockIdx.x * CHUNK_E;
        if (tid < NBUK) { h1[tid] = 0; h2[tid] = 0; }
        __syncthreads();
        for (int e = e0 + tid; e < e0 + CHUNK_E; e += 256) {
            atomicAdd(&h1[dst[e] >> BSH], 1);
            atomicAdd(&h2[src[e] >> BSH], 1);
        }
        __syncthreads();
        if (tid < NBUK) {
            int c = h1[tid];
            b1[tid] = (c > 0) ? atomicAdd(&pcnt[tid], c) : 0;
            c1[tid] = 0;
            int d = h2[tid];
            b2[tid] = (d > 0) ? atomicAdd(&scnt[tid], d) : 0;
            c2[tid] = 0;
        }
        __syncthreads();
        for (int e = e0 + tid; e < e0 + CHUNK_E; e += 256) {
            int d = dst[e];
            int s = src[e];
            int bb = d >> BSH;
            int r = atomicAdd(&c1[bb], 1);
            pbuf[bb * PCAP + b1[bb] + r] = ((uint)(d & (BNODES - 1)) << 17) | (uint)s;
            int sb = s >> BSH;
            int r2 = atomicAdd(&c2[sb], 1);
            sbuf[sb * SCAP + b2[sb] + r2] = (ushort)(s & (BNODES - 1));
        }
    } else {
        int idx = (blockIdx.x - CHUNKS) * 512 + tid * 2;  // 65536 total
        int k0 = idx >> 8, n0 = idx & 255;
        reinterpret_cast<__fp16*>(Wt1)[n0 * DIM + k0] = (__fp16)W1[idx];
        int idx1 = idx + 1;
        int k1 = idx1 >> 8, n1 = idx1 & 255;
        reinterpret_cast<__fp16*>(Wt1)[n1 * DIM + k1] = (__fp16)W1[idx1];
    }
}

// ---- K2 FUSED: exclusive scan of pair counts -> boff | per-bucket src count -> onorm ----
__global__ __launch_bounds__(256) void k_scan_onorm(const int* __restrict__ pcnt,
                                                    int* __restrict__ boff,
                                                    const int* __restrict__ scnt,
                                                    const ushort* __restrict__ sbuf,
                                                    float* __restrict__ onorm) {
    int t = threadIdx.x;
    if (blockIdx.x == 0) {
        __shared__ int sm[256];
        int v = (t < NBUK) ? pcnt[t] : 0;
        sm[t] = v;
        __syncthreads();
        for (int off = 1; off < 256; off <<= 1) {
            int u = (t >= off) ? sm[t - off] : 0;
            __syncthreads();
            sm[t] += u;
            __syncthreads();
        }
        if (t < NBUK) boff[t] = sm[t] - v;
        if (t == 255) boff[NBUK] = sm[255];
    } else {
        __shared__ int hist[BNODES];
        int b = blockIdx.x - 1;
        hist[t] = 0;
        hist[t + 256] = 0;
        __syncthreads();
        int n = scnt[b];
        const ushort* sp = sbuf + (size_t)b * SCAP;
        for (int i = t; i < n; i += 256) atomicAdd(&hist[sp[i]], 1);
        __syncthreads();
        int node0 = b << BSH;
#pragma unroll
        for (int k = t; k < BNODES; k += 256) {
            int node = node0 + k;
            if (node < NN) {
                int v = hist[k];
                onorm[node] = v > 0 ? rsqrtf((float)v) : 0.f;
            }
        }
    }
}

// ---- K3 FUSED: per-bucket CSR finalize (LDS hist+scan+scatter) | embed + onorm prescale ----
__global__ __launch_bounds__(1024) void k_bsort_embed(const uint* __restrict__ pbuf,
                                                      const int* __restrict__ boff,
                                                      int* __restrict__ col,
                                                      int* __restrict__ rowptr,
                                                      float* __restrict__ inorm,
                                                      const int* __restrict__ feat,
                                                      const float* __restrict__ emb,
                                                      const float* __restrict__ onorm,
                                                      ushort* __restrict__ h) {
    __shared__ int hist[BNODES];
    __shared__ int sc[BNODES];
    __shared__ int ex[BNODES];
    __shared__ int cur[BNODES];
    __shared__ int colbuf[COLBUF_CAP];
    int t = threadIdx.x;
    if (blockIdx.x < NBUK) {
        int b = blockIdx.x;
        int o0 = boff[b];
        int n = boff[b + 1] - o0;
        const uint* pp = pbuf + (size_t)b * PCAP;

        if (t < BNODES) hist[t] = 0;
        __syncthreads();
        for (int i = t; i < n; i += 1024) atomicAdd(&hist[pp[i] >> 17], 1);
        __syncthreads();
        int v = (t < BNODES) ? hist[t] : 0;
        if (t < BNODES) sc[t] = v;
        __syncthreads();
        for (int off = 1; off < BNODES; off <<= 1) {
            int u = (t < BNODES && t >= off) ? sc[t - off] : 0;
            __syncthreads();
            if (t < BNODES) sc[t] += u;
            __syncthreads();
        }
        if (t < BNODES) {
            ex[t] = sc[t] - v;
            cur[t] = 0;
            int node = (b << BSH) + t;
            if (node < NN) {
                rowptr[node] = o0 + ex[t];
                inorm[node] = v > 0 ? rsqrtf((float)v) : 0.f;
            }
        }
        if (b == NBUK - 1 && t == 0) rowptr[NN] = NE;
        __syncthreads();

        if (n <= COLBUF_CAP) {
            for (int i = t; i < n; i += 1024) {
                uint p = pp[i];
                int ld = p >> 17;
                int r = atomicAdd(&cur[ld], 1);
                colbuf[ex[ld] + r] = (int)(p & 0x1FFFF);
            }
            __syncthreads();
            for (int i = t; i < n; i += 1024) col[o0 + i] = colbuf[i];
        } else {  // statistically unreachable fallback
            for (int i = t; i < n; i += 1024) {
                uint p = pp[i];
                int ld = p >> 17;
                int r = atomicAdd(&cur[ld], 1);
                col[o0 + ex[ld] + r] = (int)(p & 0x1FFFF);
            }
        }
    } else {
        int idx = (blockIdx.x - NBUK) * 1024 + t;  // NN*64 total
        int node = idx >> 6;
        int g = idx & 63;
        if (node >= NN) return;
        const int4 f = *reinterpret_cast<const int4*>(feat + node * 4);
        const float4* emb4 = reinterpret_cast<const float4*>(emb);
        float4 a = emb4[(long)f.x * 64 + g];
        float4 b = emb4[(long)f.y * 64 + g];
        float4 c = emb4[(long)f.z * 64 + g];
        float4 d = emb4[(long)f.w * 64 + g];
        float scn = onorm[node];
        float4 r;
        r.x = (a.x + b.x + c.x + d.x) * scn;
        r.y = (a.y + b.y + c.y + d.y) * scn;
        r.z = (a.z + b.z + c.z + d.z) * scn;
        r.w = (a.w + b.w + c.w + d.w) * scn;
        reinterpret_cast<uint2*>(h)[(long)node * 64 + g] = f4_to_h4(r);
    }
}

// ---------------- aggregation: one wave per dst node ----------------
// MODE 0: hout = relu(acc * inorm) * onorm ; MODE 1: hout = acc * inorm
template <int MODE>
__global__ void k_agg(const int* __restrict__ rowptr, const int* __restrict__ col,
                      const ushort* __restrict__ hin, const float* __restrict__ inorm,
                      const float* __restrict__ onorm, ushort* __restrict__ hout) {
    int wid = (blockIdx.x * blockDim.x + threadIdx.x) >> 6;
    int lane = threadIdx.x & 63;
    if (wid >= NN) return;
    int half = lane >> 5;
    int l32 = lane & 31;
    int e0 = rowptr[wid];
    int e1 = rowptr[wid + 1];
    const uint4* hin4 = reinterpret_cast<const uint4*>(hin);
    float4 aA0 = {0,0,0,0}, aA1 = {0,0,0,0};
    float4 aB0 = {0,0,0,0}, aB1 = {0,0,0,0};
    int e = e0;
    for (; e + 8 <= e1; e += 8) {
        int s0 = col[e + 0 + half];
        int s1 = col[e + 2 + half];
        int s2 = col[e + 4 + half];
        int s3 = col[e + 6 + half];
        uint4 u0 = hin4[(long)s0 * 32 + l32];
        uint4 u1 = hin4[(long)s1 * 32 + l32];
        uint4 u2 = hin4[(long)s2 * 32 + l32];
        uint4 u3 = hin4[(long)s3 * 32 + l32];
        add8(aA0, aA1, u0);
        add8(aB0, aB1, u1);
        add8(aA0, aA1, u2);
        add8(aB0, aB1, u3);
    }
    for (; e < e1; e += 2) {
        int idx = e + half;
        if (idx < e1) {
            int s = col[idx];
            uint4 u = hin4[(long)s * 32 + l32];
            add8(aA0, aA1, u);
        }
    }
    float f[8];
    f[0] = aA0.x + aB0.x; f[1] = aA0.y + aB0.y; f[2] = aA0.z + aB0.z; f[3] = aA0.w + aB0.w;
    f[4] = aA1.x + aB1.x; f[5] = aA1.y + aB1.y; f[6] = aA1.z + aB1.z; f[7] = aA1.w + aB1.w;
#pragma unroll
    for (int j = 0; j < 8; ++j) f[j] += __shfl_xor(f[j], 32);

    float scn = inorm[wid];
    float4 r0, r1;
    if (MODE == 0) {
        float on = onorm[wid];
        r0.x = fmaxf(f[0] * scn, 0.f) * on;
        r0.y = fmaxf(f[1] * scn, 0.f) * on;
        r0.z = fmaxf(f[2] * scn, 0.f) * on;
        r0.w = fmaxf(f[3] * scn, 0.f) * on;
        r1.x = fmaxf(f[4] * scn, 0.f) * on;
        r1.y = fmaxf(f[5] * scn, 0.f) * on;
        r1.z = fmaxf(f[6] * scn, 0.f) * on;
        r1.w = fmaxf(f[7] * scn, 0.f) * on;
    } else {
        r0.x = f[0] * scn; r0.y = f[1] * scn; r0.z = f[2] * scn; r0.w = f[3] * scn;
        r1.x = f[4] * scn; r1.y = f[5] * scn; r1.z = f[6] * scn; r1.w = f[7] * scn;
    }
    if (half == 0) {
        uint2 lo = f4_to_h4(r0);
        uint2 hi = f4_to_h4(r1);
        uint4 o; o.x = lo.x; o.y = lo.y; o.z = hi.x; o.w = hi.y;
        reinterpret_cast<uint4*>(hout)[(long)wid * 32 + l32] = o;
    }
}

// ---------------- MFMA GEMM: y[NN,256] = x[NN,256] @ W[256,256] ----------------
__global__ __launch_bounds__(512, 2) void k_gemm(const ushort* __restrict__ x,
                                                 const ushort* __restrict__ Wt,
                                                 ushort* __restrict__ y) {
    __shared__ char wl[131072];
    int tid = threadIdx.x;
    const uint4* Wt4 = reinterpret_cast<const uint4*>(Wt);
#pragma unroll
    for (int it = 0; it < 16; ++it) {
        int chunk = it * 512 + tid;      // 0..8191 16B-chunks
        int n = chunk >> 5;              // row 0..255
        int c16 = chunk & 31;
        uint4 v = Wt4[chunk];
        int off = ((n << 9) + (c16 << 4)) ^ ((n & 7) << 4);
        *reinterpret_cast<uint4*>(&wl[off]) = v;
    }
    __syncthreads();

    int w = tid >> 6;
    int l = tid & 63;
    int wrow = blockIdx.x * 384 + w * 48;
    int lrow = l & 15;
    int lk = l >> 4;

    f32x4 acc[3][16];
#pragma unroll
    for (int m = 0; m < 3; ++m)
#pragma unroll
        for (int n = 0; n < 16; ++n) acc[m][n] = {0.f, 0.f, 0.f, 0.f};

    const char* xb = reinterpret_cast<const char*>(x);
    int r0 = wrow + lrow;
    int r1 = r0 + 16;
    int r2 = r0 + 32;
    r0 = r0 < NN ? r0 : NN - 1;
    r1 = r1 < NN ? r1 : NN - 1;
    r2 = r2 < NN ? r2 : NN - 1;

#pragma unroll
    for (int ks = 0; ks < DIM; ks += 32) {
        long kbyte = (long)(ks + lk * 8) * 2;
        half8 a0 = *reinterpret_cast<const half8*>(xb + (long)r0 * 512 + kbyte);
        half8 a1 = *reinterpret_cast<const half8*>(xb + (long)r1 * 512 + kbyte);
        half8 a2 = *reinterpret_cast<const half8*>(xb + (long)r2 * 512 + kbyte);
#pragma unroll
        for (int fn = 0; fn < 16; ++fn) {
            int n = fn * 16 + lrow;
            int off = ((n << 9) + (int)kbyte) ^ ((n & 7) << 4);
            half8 bb = *reinterpret_cast<const half8*>(&wl[off]);
            acc[0][fn] = __builtin_amdgcn_mfma_f32_16x16x32_f16(a0, bb, acc[0][fn], 0, 0, 0);
            acc[1][fn] = __builtin_amdgcn_mfma_f32_16x16x32_f16(a1, bb, acc[1][fn], 0, 0, 0);
            acc[2][fn] = __builtin_amdgcn_mfma_f32_16x16x32_f16(a2, bb, acc[2][fn], 0, 0, 0);
        }
    }

    __fp16* yh = reinterpret_cast<__fp16*>(y);
#pragma unroll
    for (int m = 0; m < 3; ++m) {
        int rbase = wrow + m * 16 + lk * 4;
#pragma unroll
        for (int fn = 0; fn < 16; ++fn) {
            int colc = fn * 16 + lrow;
#pragma unroll
            for (int r = 0; r < 4; ++r) {
                int row = rbase + r;
                if (row < NN) yh[(long)row * DIM + colc] = (__fp16)acc[m][fn][r];
            }
        }
    }
}

// ---------------- per-graph sum pooling (graph_ids sorted) -> P fp32 ----------------
__device__ inline int lbound(const int* __restrict__ a, int n, int v) {
    int lo = 0, hi = n;
    while (lo < hi) {
        int m = (lo + hi) >> 1;
        if (a[m] < v) lo = m + 1; else hi = m;
    }
    return lo;
}

__global__ __launch_bounds__(256) void k_pool(const ushort* __restrict__ h,
                                              const int* __restrict__ gids,
                                              float* __restrict__ P) {
    int g = blockIdx.x;
    int t = threadIdx.x;
    int lo = lbound(gids, NN, g);
    int hi = lbound(gids, NN, g + 1);
    const __fp16* hh = reinterpret_cast<const __fp16*>(h);
    float acc = 0.f;
    for (int nd = lo; nd < hi; ++nd) acc += (float)hh[(long)nd * DIM + t];
    P[(long)g * DIM + t] = acc;
}

// ---------------- mini-GEMM: out[NG,256] = P[NG,256] @ W2[256,256] (fp32) ----------------
__global__ __launch_bounds__(256) void k_pgemm(const float* __restrict__ P,
                                               const float* __restrict__ W2,
                                               float* __restrict__ out) {
    __shared__ float Pl[8][DIM];
    int t = threadIdx.x;
    int rbase = blockIdx.x * 8;
#pragma unroll
    for (int r = 0; r < 8; ++r) Pl[r][t] = P[(long)(rbase + r) * DIM + t];
    __syncthreads();
    float acc[8];
#pragma unroll
    for (int r = 0; r < 8; ++r) acc[r] = 0.f;
    for (int k = 0; k < DIM; ++k) {
        float w = W2[(long)k * DIM + t];
#pragma unroll
        for (int r = 0; r < 8; ++r) acc[r] += Pl[r][k] * w;
    }
#pragma unroll
    for (int r = 0; r < 8; ++r) out[(long)(rbase + r) * DIM + t] = acc[r];
}

extern "C" void kernel_launch(void* const* d_in, const int* in_sizes, int n_in,
                              void* d_out, int out_size, void* d_ws, size_t ws_size,
                              hipStream_t stream) {
    const int* feature = (const int*)d_in[0];
    const int* src = (const int*)d_in[1];
    const int* dst = (const int*)d_in[2];
    const int* gids = (const int*)d_in[3];
    const float* emb = (const float*)d_in[4];
    const float* W1 = (const float*)d_in[5];
    const float* W2 = (const float*)d_in[6];
    float* out = (float*)d_out;

    // workspace carve (all 16B aligned)
    char* p = (char*)d_ws;
    ushort* hA = (ushort*)p;            p += (size_t)NN * DIM * 2;
    ushort* hB = (ushort*)p;            p += (size_t)NN * DIM * 2;
    ushort* Wt1 = (ushort*)p;           p += (size_t)DIM * DIM * 2;
    float* onorm = (float*)p;           p += (size_t)NN * 4;
    float* inorm = (float*)p;           p += (size_t)NN * 4;
    int* rowptr = (int*)p;              p += (size_t)(NN + 4) * 4;
    int* colidx = (int*)p;              p += (size_t)NE * 4;
    int* pcnt = (int*)p;                p += (size_t)NBUK * 4;        // zeroed
    int* scnt = (int*)p;                p += (size_t)NBUK * 4;        // zeroed (adjacent)
    int* boff = (int*)p;                p += (size_t)(NBUK + 4) * 4;
    uint* pbuf = (uint*)p;              p += (size_t)NBUK * PCAP * 4;
    ushort* sbuf = (ushort*)p;          p += (size_t)NBUK * SCAP * 2;
    float* Pbuf = (float*)p;            p += (size_t)NG * DIM * 4;

    // zero the two 196-counter arrays (adjacent)
    hipMemsetAsync(pcnt, 0, (size_t)2 * NBUK * 4, stream);

    // K1: dual bucket scatter | W1 -> Wt1
    k_scatter2<<<CHUNKS + WCONV_BLK, 256, 0, stream>>>(src, dst, pcnt, scnt,
                                                       pbuf, sbuf, W1, Wt1);
    // K2: boff scan | src counts -> onorm
    k_scan_onorm<<<1 + NBUK, 256, 0, stream>>>(pcnt, boff, scnt, sbuf, onorm);
    // K3: per-bucket CSR finalize | embed (+onorm prescale)
    k_bsort_embed<<<NBUK + EMB_BLK1K, 1024, 0, stream>>>(pbuf, boff, colidx, rowptr, inorm,
                                                         feature, emb, onorm, hA);

    const int aggGrid = (NN * 64 + 255) / 256;
    const int gemmGrid = (NN + 383) / 384;
    // layer 0 (no W): hB = relu(agg(hA) * inorm) * onorm
    k_agg<0><<<aggGrid, 256, 0, stream>>>(rowptr, colidx, hA, inorm, onorm, hB);
    // layer 1: hA = hB @ W1 ; hB = relu(agg(hA) * inorm) * onorm
    k_gemm<<<gemmGrid, 512, 0, stream>>>(hB, Wt1, hA);
    k_agg<0><<<aggGrid, 256, 0, stream>>>(rowptr, colidx, hA, inorm, onorm, hB);
    // layer 2 (W2 hoisted past agg+pool by linearity): hA = agg(hB) * inorm
    k_agg<1><<<aggGrid, 256, 0, stream>>>(rowptr, colidx, hB, inorm, onorm, hA);
    // P = pool(hA) ; out = P @ W2
    k_pool<<<NG, 256, 0, stream>>>(hA, gids, Pbuf);
    k_pgemm<<<NG / 8, 256, 0, stream>>>(Pbuf, W2, out);
}